// Round 4
// baseline (217.413 us; speedup 1.0000x reference)
//
#include <hip/hip_runtime.h>

#define NB   4
#define SEQ  4096
#define EMB  1024
#define HS   64

typedef __attribute__((ext_vector_type(8))) short bf16x8;   // 8 bf16 = 4 VGPRs
typedef __attribute__((ext_vector_type(4))) float f32x4;    // MFMA C/D

__device__ inline unsigned short f2bf(float f) {  // fp32 -> bf16 RNE
  unsigned int u = __float_as_uint(f);
  u += 0x7fffu + ((u >> 16) & 1u);
  return (unsigned short)(u >> 16);
}
__device__ inline float bf2f(unsigned short h) {
  return __uint_as_float(((unsigned int)h) << 16);
}
// 16B-chunk index in a [row][64] bf16 LDS tile, XOR-swizzled over row&7.
__device__ inline int swzi64(int row, int c) {
  return row * 64 + ((c ^ (row & 7)) << 3);
}
// [row][128] tiles (16 chunks/row, swizzle over row&7)
__device__ inline int swzi128(int row, int c) {
  return row * 128 + ((c ^ (row & 7)) << 3);
}
// Async global->LDS 16B. LDS dest wave-uniform; lane i lands at +16*i.
__device__ inline void gld16(const unsigned short* g, unsigned short* l) {
  __builtin_amdgcn_global_load_lds(
      (const __attribute__((address_space(1))) void*)g,
      (__attribute__((address_space(3))) void*)l, 16, 0, 0);
}

// ---------------------------------------------------------------------------
// W prep: split Wq*scale*log2e | Wk | Wv into bf16 hi/lo [192][1024].
// ---------------------------------------------------------------------------
__global__ __launch_bounds__(256) void wprep(
    const float* __restrict__ Wk, const float* __restrict__ Wq,
    const float* __restrict__ Wv,
    unsigned short* __restrict__ Wh, unsigned short* __restrict__ Wl) {
  int i = blockIdx.x * 256 + threadIdx.x;  // float4 id, 192*1024/4 = 49152
  int e = i >> 8, c = i & 255;
  float4 v;
  float sc = 1.0f;
  if (e < 64)       { v = ((const float4*)Wq)[e * 256 + c];
                      sc = 0.18033688011112042f; }  // (1/sqrt(64))*log2(e)
  else if (e < 128)   v = ((const float4*)Wk)[(e - 64) * 256 + c];
  else                v = ((const float4*)Wv)[(e - 128) * 256 + c];
  v.x *= sc; v.y *= sc; v.z *= sc; v.w *= sc;
  ushort4 hv, lv;
  hv.x = f2bf(v.x); lv.x = f2bf(v.x - bf2f(hv.x));
  hv.y = f2bf(v.y); lv.y = f2bf(v.y - bf2f(hv.y));
  hv.z = f2bf(v.z); lv.z = f2bf(v.z - bf2f(hv.z));
  hv.w = f2bf(v.w); lv.w = f2bf(v.w - bf2f(hv.w));
  *(ushort4*)&Wh[i * 4] = hv;
  *(ushort4*)&Wl[i * 4] = lv;
}

// ---------------------------------------------------------------------------
// Single-pass fused QKV GEMM, round 4: NO LDS, NO BARRIERS.
// Each wave is an independent 32-row x 48-col GEMM strip. A-fragment (X) is
// read DIRECTLY from global fp32 (two float4 = 8 consecutive floats per
// lane) and converted to bf16 hi/lo in registers; B-fragment (W) is a
// contiguous ushort8 of Wh/Wl (proven round 3). Register ping-pong 1-deep
// on both A(raw) and B; waves slip freely -- no lockstep, no LDS aliasing,
// no barrier drain. (Rounds 1-3: all barrier-coupled variants stuck at
// 58-65 us with ~90% idle; this removes the coupling class entirely.)
// Grid 512 x 256thr (4 waves); wave w owns n-range [48w,48w+48).
// ---------------------------------------------------------------------------
struct Araw { float4 x0, x1, y0, y1; };   // mfrag0 (rows li), mfrag1 (rows 16+li)
struct Bfr  { bf16x8 h0, h1, h2, l0, l1, l2; };

__global__ __launch_bounds__(256) void qkv_x1(
    const float* __restrict__ x,
    const unsigned short* __restrict__ Wh, const unsigned short* __restrict__ Wl,
    unsigned short* __restrict__ qh, unsigned short* __restrict__ ql,
    unsigned short* __restrict__ kh, unsigned short* __restrict__ kl,
    unsigned short* __restrict__ vt) {
  const int t  = threadIdx.x;
  const int l  = t & 63;
  const int li = l & 15;
  const int g  = l >> 4;
  const int w  = t >> 6;         // 0..3
  const int m0 = blockIdx.x * 32;
  const int b  = m0 >> 12;
  const int n0 = m0 & 4095;

  // A (X) row bases: 8 consecutive floats per lane per m-frag
  const float* const xr0 = x + (m0 + li) * EMB + 8 * g;
  const float* const xr1 = x + (m0 + 16 + li) * EMB + 8 * g;

  // B (W) row bases (this wave's 3 B-columns, this lane's row)
  const int r0 = 48 * w + li, r1 = r0 + 16, r2 = r0 + 32;
  const unsigned short* const Wh0 = Wh + r0 * EMB + 8 * g;
  const unsigned short* const Wh1 = Wh + r1 * EMB + 8 * g;
  const unsigned short* const Wh2 = Wh + r2 * EMB + 8 * g;
  const unsigned short* const Wl0 = Wl + r0 * EMB + 8 * g;
  const unsigned short* const Wl1 = Wl + r1 * EMB + 8 * g;
  const unsigned short* const Wl2 = Wl + r2 * EMB + 8 * g;

  f32x4 acc[2][3];
#pragma unroll
  for (int i = 0; i < 2; ++i)
#pragma unroll
    for (int j = 0; j < 3; ++j) acc[i][j] = (f32x4){0.f, 0.f, 0.f, 0.f};

  auto loadA = [&](int s) {
    Araw A;
    const int ko = s * 32;
    A.x0 = *(const float4*)(xr0 + ko);
    A.x1 = *(const float4*)(xr0 + ko + 4);
    A.y0 = *(const float4*)(xr1 + ko);
    A.y1 = *(const float4*)(xr1 + ko + 4);
    return A;
  };
  auto loadB = [&](int s) {
    Bfr B;
    const int ko = s * 32;
    B.h0 = *(const bf16x8*)&Wh0[ko];
    B.h1 = *(const bf16x8*)&Wh1[ko];
    B.h2 = *(const bf16x8*)&Wh2[ko];
    B.l0 = *(const bf16x8*)&Wl0[ko];
    B.l1 = *(const bf16x8*)&Wl1[ko];
    B.l2 = *(const bf16x8*)&Wl2[ko];
    return B;
  };
  auto cvtpair = [&](const float4& u, const float4& v, bf16x8& hi, bf16x8& lo) {
    const unsigned short h0 = f2bf(u.x), h1 = f2bf(u.y);
    const unsigned short h2 = f2bf(u.z), h3 = f2bf(u.w);
    const unsigned short h4 = f2bf(v.x), h5 = f2bf(v.y);
    const unsigned short h6 = f2bf(v.z), h7 = f2bf(v.w);
    hi = (bf16x8){(short)h0, (short)h1, (short)h2, (short)h3,
                  (short)h4, (short)h5, (short)h6, (short)h7};
    lo = (bf16x8){(short)f2bf(u.x - bf2f(h0)), (short)f2bf(u.y - bf2f(h1)),
                  (short)f2bf(u.z - bf2f(h2)), (short)f2bf(u.w - bf2f(h3)),
                  (short)f2bf(v.x - bf2f(h4)), (short)f2bf(v.y - bf2f(h5)),
                  (short)f2bf(v.z - bf2f(h6)), (short)f2bf(v.w - bf2f(h7))};
  };
  auto compute = [&](const Araw& A, const Bfr& B) {
    bf16x8 ah0, al0, ah1, al1;
    cvtpair(A.x0, A.x1, ah0, al0);
    cvtpair(A.y0, A.y1, ah1, al1);
    __builtin_amdgcn_s_setprio(1);
    acc[0][0] = __builtin_amdgcn_mfma_f32_16x16x32_bf16(ah0, B.h0, acc[0][0], 0,0,0);
    acc[0][0] = __builtin_amdgcn_mfma_f32_16x16x32_bf16(ah0, B.l0, acc[0][0], 0,0,0);
    acc[0][0] = __builtin_amdgcn_mfma_f32_16x16x32_bf16(al0, B.h0, acc[0][0], 0,0,0);
    acc[0][1] = __builtin_amdgcn_mfma_f32_16x16x32_bf16(ah0, B.h1, acc[0][1], 0,0,0);
    acc[0][1] = __builtin_amdgcn_mfma_f32_16x16x32_bf16(ah0, B.l1, acc[0][1], 0,0,0);
    acc[0][1] = __builtin_amdgcn_mfma_f32_16x16x32_bf16(al0, B.h1, acc[0][1], 0,0,0);
    acc[0][2] = __builtin_amdgcn_mfma_f32_16x16x32_bf16(ah0, B.h2, acc[0][2], 0,0,0);
    acc[0][2] = __builtin_amdgcn_mfma_f32_16x16x32_bf16(ah0, B.l2, acc[0][2], 0,0,0);
    acc[0][2] = __builtin_amdgcn_mfma_f32_16x16x32_bf16(al0, B.h2, acc[0][2], 0,0,0);
    acc[1][0] = __builtin_amdgcn_mfma_f32_16x16x32_bf16(ah1, B.h0, acc[1][0], 0,0,0);
    acc[1][0] = __builtin_amdgcn_mfma_f32_16x16x32_bf16(ah1, B.l0, acc[1][0], 0,0,0);
    acc[1][0] = __builtin_amdgcn_mfma_f32_16x16x32_bf16(al1, B.h0, acc[1][0], 0,0,0);
    acc[1][1] = __builtin_amdgcn_mfma_f32_16x16x32_bf16(ah1, B.h1, acc[1][1], 0,0,0);
    acc[1][1] = __builtin_amdgcn_mfma_f32_16x16x32_bf16(ah1, B.l1, acc[1][1], 0,0,0);
    acc[1][1] = __builtin_amdgcn_mfma_f32_16x16x32_bf16(al1, B.h1, acc[1][1], 0,0,0);
    acc[1][2] = __builtin_amdgcn_mfma_f32_16x16x32_bf16(ah1, B.h2, acc[1][2], 0,0,0);
    acc[1][2] = __builtin_amdgcn_mfma_f32_16x16x32_bf16(ah1, B.l2, acc[1][2], 0,0,0);
    acc[1][2] = __builtin_amdgcn_mfma_f32_16x16x32_bf16(al1, B.h2, acc[1][2], 0,0,0);
    __builtin_amdgcn_s_setprio(0);
  };

  // register ping-pong, manual unroll-by-2 (static indexing, rule #20)
  Araw Aa = loadA(0), Ab;
  Bfr  Ba = loadB(0), Bb;
  for (int s2 = 0; s2 < 16; ++s2) {
    const int s = 2 * s2;
    if (s < 31) { Ab = loadA(s + 1); Bb = loadB(s + 1); }
    compute(Aa, Ba);
    if (s + 1 < 31) { Aa = loadA(s + 2); Ba = loadB(s + 2); }
    compute(Ab, Bb);
  }

  // Epilogue: D[m=16i+4g+r][n=48w+16j+li]
#pragma unroll
  for (int i = 0; i < 2; ++i)
#pragma unroll
    for (int j = 0; j < 3; ++j) {
      const int H3 = 48 * w + 16 * j + li;
#pragma unroll
      for (int r = 0; r < 4; ++r) {
        const int mrow = 16 * i + 4 * g + r;
        const float vv = acc[i][j][r];
        if (H3 < 64) {
          const unsigned short hb = f2bf(vv);
          const int off = (b * SEQ + n0 + mrow) * HS + H3;
          qh[off] = hb; ql[off] = f2bf(vv - bf2f(hb));
        } else if (H3 < 128) {
          const unsigned short hb = f2bf(vv);
          const int off = (b * SEQ + n0 + mrow) * HS + (H3 - 64);
          kh[off] = hb; kl[off] = f2bf(vv - bf2f(hb));
        } else {
          vt[(b * HS + (H3 - 128)) * SEQ + n0 + mrow] = f2bf(vv);
        }
      }
    }
}

// ---------------------------------------------------------------------------
// Flash attention, MFMA, cheap softmax (C-init=-32, truncated P, per-lane l).
// Grid (64, NB): 64 q-rows/block, 512 thr = 8 waves = 2 waves/SIMD.
// Wave w = (qg = w&1, ks = w>>1): 32 q (TWO MFMA B-sets sharing every
// K-fragment read) x 32 keys of the 128-key staged tile. 32 iters.
// K/V staging DOUBLE-BUFFERED (T3 minimum-2-phase): tile t+1's gld16s issue
// BEFORE compute of tile t; ONE barrier/iter whose implicit vmcnt(0) drain
// lands after compute -> staging latency hidden. (K/V segs are consumed
// cross-wave, so the vmcnt(0)-in-syncthreads IS required here, unlike qkv.)
// LDS 116KB; grid=1 block/CU. s_setprio(1) around MFMA clusters (T5).
// End merge of the 4 key-slices + l via LDS (staging reused).
// ---------------------------------------------------------------------------
__global__ __launch_bounds__(512) void attn_mfma(
    const unsigned short* __restrict__ qh, const unsigned short* __restrict__ ql,
    const unsigned short* __restrict__ kh, const unsigned short* __restrict__ kl,
    const unsigned short* __restrict__ vt, float* __restrict__ out) {
  __shared__ __align__(16) unsigned char SM[118784];
  // layout: Kh[p] @ p*16384 (2x16KB), Kl[p] @ 32768+p*16384 (2x16KB),
  //         Vt[p] @ 65536+p*16384 (2x16KB), Pt @ 98304 (20KB)
  unsigned short* const PtS = (unsigned short*)(SM + 98304);  // 8 x 1280 ush

  const int t  = threadIdx.x;
  const int l  = t & 63;
  const int li = l & 15;
  const int g  = l >> 4;
  const int w  = t >> 6;        // 0..7
  const int qg = w & 1;
  const int ks = w >> 1;        // key slice 0..3
  const int b  = blockIdx.y;
  const int q0 = blockIdx.x << 6;

  // Persistent Q fragments, 2 q-sets (B[k=h][n=q], n=li).
  bf16x8 qfh[2][2], qfl[2][2];
#pragma unroll
  for (int qs = 0; qs < 2; ++qs) {
    const unsigned short* qrh = qh + (b * SEQ + q0 + 32 * qg + 16 * qs + li) * HS;
    const unsigned short* qrl = ql + (b * SEQ + q0 + 32 * qg + 16 * qs + li) * HS;
    qfh[qs][0] = *(const bf16x8*)&qrh[8 * g];
    qfh[qs][1] = *(const bf16x8*)&qrh[32 + 8 * g];
    qfl[qs][0] = *(const bf16x8*)&qrl[8 * g];
    qfl[qs][1] = *(const bf16x8*)&qrl[32 + 8 * g];
  }

  // gld16 lane constants. K segs: 8 key-rows x 64 h = 1KB.
  const int kconst = (l >> 3) * HS + (((l & 7) ^ (l >> 3)) << 3);
  // V segs: 4 h-rows x 128 keys = 1KB; chunk perm depends on seg parity.
  const int rowl = l >> 4, slot = l & 15;
  const int vcE = rowl * SEQ + ((slot ^ rowl) << 3);
  const int vcO = rowl * SEQ + ((slot ^ (4 + rowl)) << 3);
  const unsigned short* khB = kh + b * SEQ * HS;
  const unsigned short* klB = kl + b * SEQ * HS;
  const unsigned short* vtB = vt + b * HS * SEQ;
  const int sA = 2 * w, sB = 2 * w + 1;   // this wave's 2 segs per array

  f32x4 O[4][2];
#pragma unroll
  for (int ht = 0; ht < 4; ++ht) {
    O[ht][0] = (f32x4){0.f, 0.f, 0.f, 0.f};
    O[ht][1] = (f32x4){0.f, 0.f, 0.f, 0.f};
  }
  float lp0 = 0.f, lp1 = 0.f;
  unsigned short* const PtW = PtS + w * 1280;  // 32 q x stride 40

  // stage key-tile `it` into buffer p (issue only; NO wait here)
  auto stage = [&](int it, int p) {
    const int kt0 = it << 7;  // 128 keys per tile
    unsigned short* const KhP = (unsigned short*)(SM + p * 16384);
    unsigned short* const KlP = (unsigned short*)(SM + 32768 + p * 16384);
    unsigned short* const VtP = (unsigned short*)(SM + 65536 + p * 16384);
    gld16(khB + (kt0 + 8 * sA) * HS + kconst, KhP + sA * 512);
    gld16(khB + (kt0 + 8 * sB) * HS + kconst, KhP + sB * 512);
    gld16(klB + (kt0 + 8 * sA) * HS + kconst, KlP + sA * 512);
    gld16(klB + (kt0 + 8 * sB) * HS + kconst, KlP + sB * 512);
    gld16(vtB + 4 * sA * SEQ + kt0 + vcE, VtP + sA * 512);
    gld16(vtB + 4 * sB * SEQ + kt0 + vcO, VtP + sB * 512);
  };

  stage(0, 0);
  __syncthreads();            // drains tile 0 -> buf0 ready

  for (int it = 0; it < 32; ++it) {
    const int p = it & 1;
    if (it < 31) stage(it + 1, p ^ 1);   // flies during compute of tile it

    unsigned short* const KhS = (unsigned short*)(SM + p * 16384);
    unsigned short* const KlS = (unsigned short*)(SM + 32768 + p * 16384);
    unsigned short* const VtS = (unsigned short*)(SM + 65536 + p * 16384);

    // S[key][q]: wave's keys 32ks + 16kt + 4g + r; q-sets share A-reads.
    f32x4 S[2][2];
    S[0][0] = (f32x4){-32.f, -32.f, -32.f, -32.f};
    S[0][1] = (f32x4){-32.f, -32.f, -32.f, -32.f};
    S[1][0] = (f32x4){-32.f, -32.f, -32.f, -32.f};
    S[1][1] = (f32x4){-32.f, -32.f, -32.f, -32.f};
    __builtin_amdgcn_s_setprio(1);
#pragma unroll
    for (int khf = 0; khf < 2; ++khf) {
      const int cc = 4 * khf + g;
#pragma unroll
      for (int kt = 0; kt < 2; ++kt) {
        const int row = 32 * ks + 16 * kt + li;
        bf16x8 akh = *(const bf16x8*)&KhS[swzi64(row, cc)];
        bf16x8 akl = *(const bf16x8*)&KlS[swzi64(row, cc)];
        S[kt][0] = __builtin_amdgcn_mfma_f32_16x16x32_bf16(akh, qfh[0][khf], S[kt][0], 0,0,0);
        S[kt][0] = __builtin_amdgcn_mfma_f32_16x16x32_bf16(akh, qfl[0][khf], S[kt][0], 0,0,0);
        S[kt][0] = __builtin_amdgcn_mfma_f32_16x16x32_bf16(akl, qfh[0][khf], S[kt][0], 0,0,0);
        S[kt][1] = __builtin_amdgcn_mfma_f32_16x16x32_bf16(akh, qfh[1][khf], S[kt][1], 0,0,0);
        S[kt][1] = __builtin_amdgcn_mfma_f32_16x16x32_bf16(akh, qfl[1][khf], S[kt][1], 0,0,0);
        S[kt][1] = __builtin_amdgcn_mfma_f32_16x16x32_bf16(akl, qfh[1][khf], S[kt][1], 0,0,0);
      }
    }
    __builtin_amdgcn_s_setprio(0);

    // p = exp2(S'-32), truncate to bf16, l from truncated values.
#pragma unroll
    for (int kt = 0; kt < 2; ++kt)
#pragma unroll
      for (int qs = 0; qs < 2; ++qs) {
        unsigned pu[4];
        float ls = 0.f;
#pragma unroll
        for (int r = 0; r < 4; ++r) {
          const float pe = exp2f(S[kt][qs][r]);
          pu[r] = __float_as_uint(pe);
          ls += __uint_as_float(pu[r] & 0xffff0000u);
        }
        if (qs == 0) lp0 += ls; else lp1 += ls;
        const unsigned p01 = __builtin_amdgcn_perm(pu[1], pu[0], 0x07060302u);
        const unsigned p23 = __builtin_amdgcn_perm(pu[3], pu[2], 0x07060302u);
        const int qrow = 16 * qs + li;
        const int c = 2 * kt + (g >> 1);
        const int addr = qrow * 40 + (((c ^ (qrow & 3))) << 3) + ((g & 1) << 2);
        int2 pv; pv.x = (int)p01; pv.y = (int)p23;
        *(int2*)&PtW[addr] = pv;
      }

    asm volatile("" ::: "memory");  // Pt writes before wave-local reads

    // O^T += V^T . P over this wave's 32 keys.
    bf16x8 pb0 = *(const bf16x8*)&PtW[li * 40 + ((g ^ (li & 3)) << 3)];
    {
      const int r1 = 16 + li;
      bf16x8 pb1 = *(const bf16x8*)&PtW[r1 * 40 + ((g ^ (r1 & 3)) << 3)];
      __builtin_amdgcn_s_setprio(1);
#pragma unroll
      for (int ht = 0; ht < 4; ++ht) {
        const int vrow = 16 * ht + li;
        bf16x8 va = *(const bf16x8*)&VtS[swzi128(vrow, 4 * ks + g)];
        O[ht][0] = __builtin_amdgcn_mfma_f32_16x16x32_bf16(va, pb0, O[ht][0], 0,0,0);
        O[ht][1] = __builtin_amdgcn_mfma_f32_16x16x32_bf16(va, pb1, O[ht][1], 0,0,0);
      }
      __builtin_amdgcn_s_setprio(0);
    }

    // ONE barrier/iter: implicit vmcnt(0) drains tile it+1 (issued above,
    // in flight during all of compute) + guarantees buf[p] fully consumed
    // before it's re-staged at iteration it+1. (Cross-wave consumption ->
    // the drain IS required here.)
    __syncthreads();
  }

  // loop-final barrier: all waves done with staging -> reuse LDS for merge

  // reduce l over the 4 quads (keys) of this wave
  lp0 += __shfl_xor(lp0, 16); lp0 += __shfl_xor(lp0, 32);
  lp1 += __shfl_xor(lp1, 16); lp1 += __shfl_xor(lp1, 32);

  float* const OTm = (float*)SM;               // [8 waves][32 q][64 h] = 64KB
  float* const Lm  = (float*)(SM + 65536);     // [8 waves][32 q]
#pragma unroll
  for (int ht = 0; ht < 4; ++ht)
#pragma unroll
    for (int qs = 0; qs < 2; ++qs) {
      float4 o4;
      o4.x = O[ht][qs][0]; o4.y = O[ht][qs][1];
      o4.z = O[ht][qs][2]; o4.w = O[ht][qs][3];
      *(float4*)&OTm[w * 2048 + (16 * qs + li) * 64 + 16 * ht + 4 * g] = o4;
    }
  if (g == 0) { Lm[w * 32 + li] = lp0; Lm[w * 32 + 16 + li] = lp1; }
  __syncthreads();

  // final: thread t -> q = t>>3 (64), h8 = (t&7)*8; sum 4 key-slices.
  {
    const int q = t >> 3, h8 = (t & 7) << 3;
    const int qq = q & 31, qgf = q >> 5;
    float lF = 0.f;
    float4 a = {0.f, 0.f, 0.f, 0.f}, c4 = {0.f, 0.f, 0.f, 0.f};
#pragma unroll
    for (int k2 = 0; k2 < 4; ++k2) {
      const int ww = qgf + 2 * k2;
      lF += Lm[ww * 32 + qq];
      const float* Ob = OTm + ww * 2048 + qq * 64 + h8;
      float4 u = *(const float4*)Ob;
      float4 v = *(const float4*)(Ob + 4);
      a.x += u.x; a.y += u.y; a.z += u.z; a.w += u.w;
      c4.x += v.x; c4.y += v.y; c4.z += v.z; c4.w += v.w;
    }
    const float inv = 1.f / lF;
    a.x *= inv; a.y *= inv; a.z *= inv; a.w *= inv;
    c4.x *= inv; c4.y *= inv; c4.z *= inv; c4.w *= inv;
    float* op = out + (b * SEQ + q0 + q) * HS + h8;
    *(float4*)op = a;
    *(float4*)(op + 4) = c4;
  }
}

// ---------------------------------------------------------------------------
extern "C" void kernel_launch(void* const* d_in, const int* in_sizes, int n_in,
                              void* d_out, int out_size, void* d_ws,
                              size_t ws_size, hipStream_t stream) {
  const float* x  = (const float*)d_in[0];
  const float* Wk = (const float*)d_in[1];
  const float* Wq = (const float*)d_in[2];
  const float* Wv = (const float*)d_in[3];
  float* out = (float*)d_out;

  unsigned short* us = (unsigned short*)d_ws;
  unsigned short* qh = us + 0 * (1 << 20);   // [B][N][H] bf16 hi
  unsigned short* ql = us + 1 * (1 << 20);   // [B][N][H] bf16 lo
  unsigned short* kh = us + 2 * (1 << 20);
  unsigned short* kl = us + 3 * (1 << 20);
  unsigned short* vt = us + 4 * (1 << 20);   // [B][H][N] bf16
  unsigned short* Wh = us + 5 * (1 << 20);   // [192][1024] bf16 hi
  unsigned short* Wl = Wh + 192 * 1024;      // [192][1024] bf16 lo
  // total workspace: ~11 MB (proven available since round 3)

  wprep<<<192, 256, 0, stream>>>(Wk, Wq, Wv, Wh, Wl);
  qkv_x1<<<512, 256, 0, stream>>>(x, Wh, Wl, qh, ql, kh, kl, vt);
  attn_mfma<<<dim3(64, NB), 512, 0, stream>>>(qh, ql, kh, kl, vt, out);
}

// Round 5
// 186.167 us; speedup vs baseline: 1.1678x; 1.1678x over previous
//
#include <hip/hip_runtime.h>

#define NB   4
#define SEQ  4096
#define EMB  1024
#define HS   64

typedef __attribute__((ext_vector_type(8))) short bf16x8;   // 8 bf16 = 4 VGPRs
typedef __attribute__((ext_vector_type(4))) float f32x4;    // MFMA C/D
typedef __attribute__((ext_vector_type(4))) int   i32x4;

__device__ inline unsigned short f2bf(float f) {  // fp32 -> bf16 RNE
  unsigned int u = __float_as_uint(f);
  u += 0x7fffu + ((u >> 16) & 1u);
  return (unsigned short)(u >> 16);
}
__device__ inline float bf2f(unsigned short h) {
  return __uint_as_float(((unsigned int)h) << 16);
}
// 16B-chunk index in a [row][64] bf16 LDS tile, XOR-swizzled over row&7.
__device__ inline int swzi64(int row, int c) {
  return row * 64 + ((c ^ (row & 7)) << 3);
}
// same for [row][32] tiles (4 chunks/row, swizzle over (row>>1)&3)
__device__ inline int swzi32(int row, int c) {
  return row * 32 + ((c ^ ((row >> 1) & 3)) << 3);
}
// [row][128] tiles (16 chunks/row, swizzle over row&7)
__device__ inline int swzi128(int row, int c) {
  return row * 128 + ((c ^ (row & 7)) << 3);
}
// Async global->LDS 16B. LDS dest wave-uniform; lane i lands at +16*i.
__device__ inline void gld16(const unsigned short* g, unsigned short* l) {
  __builtin_amdgcn_global_load_lds(
      (const __attribute__((address_space(1))) void*)g,
      (__attribute__((address_space(3))) void*)l, 16, 0, 0);
}

// ---------------------------------------------------------------------------
// W prep: split Wq*scale*log2e | Wk | Wv into bf16 hi/lo [192][1024].
// ---------------------------------------------------------------------------
__global__ __launch_bounds__(256) void wprep(
    const float* __restrict__ Wk, const float* __restrict__ Wq,
    const float* __restrict__ Wv,
    unsigned short* __restrict__ Wh, unsigned short* __restrict__ Wl) {
  int i = blockIdx.x * 256 + threadIdx.x;  // float4 id, 192*1024/4 = 49152
  int e = i >> 8, c = i & 255;
  float4 v;
  float sc = 1.0f;
  if (e < 64)       { v = ((const float4*)Wq)[e * 256 + c];
                      sc = 0.18033688011112042f; }  // (1/sqrt(64))*log2(e)
  else if (e < 128)   v = ((const float4*)Wk)[(e - 64) * 256 + c];
  else                v = ((const float4*)Wv)[(e - 128) * 256 + c];
  v.x *= sc; v.y *= sc; v.z *= sc; v.w *= sc;
  ushort4 hv, lv;
  hv.x = f2bf(v.x); lv.x = f2bf(v.x - bf2f(hv.x));
  hv.y = f2bf(v.y); lv.y = f2bf(v.y - bf2f(hv.y));
  hv.z = f2bf(v.z); lv.z = f2bf(v.z - bf2f(hv.z));
  hv.w = f2bf(v.w); lv.w = f2bf(v.w - bf2f(hv.w));
  *(ushort4*)&Wh[i * 4] = hv;
  *(ushort4*)&Wl[i * 4] = lv;
}

// ---------------------------------------------------------------------------
// Single-pass fused QKV GEMM (round-2 structure, best measured 58.4 us):
// C[32 x 192] per block = x-tile . [Wq|Wk|Wv]^T, split-bf16
// (acc += Ah.Bh + Ah.Bl + Al.Bh). Grid 512, 256 thr = 4 waves,
// wave w owns n-range [48w, 48w+48) x full m=32 (2x3 16x16 C-tiles).
// BK=32, 32 stages, double-buffered; counted-vmcnt pipeline (T4): wave w
// consumes ONLY the W segments it stages itself, so W sync is per-wave
// vmcnt; loop barrier is raw lgkmcnt(0)+s_barrier (X ds_write visibility),
// NO vmcnt(0) drain. writeX(px) use auto-inserts vmcnt(6).
// ---------------------------------------------------------------------------
#define XhSp(p) ((unsigned short*)(SM + (p) * 2048))
#define XlSp(p) ((unsigned short*)(SM + 4096 + (p) * 2048))
#define WhSp(p) ((unsigned short*)(SM + 8192 + (p) * 12288))
#define WlSp(p) ((unsigned short*)(SM + 32768 + (p) * 12288))

__global__ __launch_bounds__(256) void qkv_x1(
    const float* __restrict__ x,
    const unsigned short* __restrict__ Wh, const unsigned short* __restrict__ Wl,
    unsigned short* __restrict__ qh, unsigned short* __restrict__ ql,
    unsigned short* __restrict__ kh, unsigned short* __restrict__ kl,
    unsigned short* __restrict__ vt) {
  __shared__ __align__(16) unsigned char SM[57344];

  const int t  = threadIdx.x;
  const int l  = t & 63;
  const int li = l & 15;
  const int g  = l >> 4;
  const int w  = t >> 6;         // 0..3
  const int m0 = blockIdx.x * 32;
  const int b  = m0 >> 12;
  const int n0 = m0 & 4095;

  // x load/convert map: thread -> one float4 of the 32x32 tile
  const int xrow = t >> 3;
  const float* xp = x + (m0 + xrow) * EMB + (t & 7) * 4;
  const int xaddr = xrow * 32 + ((((t & 7) >> 1) ^ ((xrow >> 1) & 3)) << 3)
                    + (t & 1) * 4;

  // W gld16 lane-constant (seg = 16 W-rows x 32 k = 1KB)
  const int wconst = (l >> 2) * EMB + (((l & 3) ^ ((l >> 3) & 3)) << 3);

  f32x4 acc[2][3];
#pragma unroll
  for (int i = 0; i < 2; ++i)
#pragma unroll
    for (int j = 0; j < 3; ++j) acc[i][j] = (f32x4){0.f, 0.f, 0.f, 0.f};

  const int rA0 = li, rA1 = 16 + li;
  const int rB0 = 48 * w + li, rB1 = rB0 + 16, rB2 = rB0 + 32;

  auto issueW = [&](int s, int p) {
    const int ko = s * 32;
#pragma unroll
    for (int i = 0; i < 3; ++i) {
      const int seg = 3 * w + i;
      gld16(Wh + 16 * seg * EMB + wconst + ko, WhSp(p) + seg * 512);
      gld16(Wl + 16 * seg * EMB + wconst + ko, WlSp(p) + seg * 512);
    }
  };
  auto writeX = [&](float4 v, int p) {
    unsigned short h0 = f2bf(v.x), h1 = f2bf(v.y), h2 = f2bf(v.z), h3 = f2bf(v.w);
    unsigned short e0 = f2bf(v.x - bf2f(h0)), e1 = f2bf(v.y - bf2f(h1));
    unsigned short e2 = f2bf(v.z - bf2f(h2)), e3 = f2bf(v.w - bf2f(h3));
    int2 hv, lv;
    hv.x = (int)((unsigned)h0 | ((unsigned)h1 << 16));
    hv.y = (int)((unsigned)h2 | ((unsigned)h3 << 16));
    lv.x = (int)((unsigned)e0 | ((unsigned)e1 << 16));
    lv.y = (int)((unsigned)e2 | ((unsigned)e3 << 16));
    *(int2*)&XhSp(p)[xaddr] = hv;
    *(int2*)&XlSp(p)[xaddr] = lv;
  };

  float4 px = *(const float4*)xp;     // stage 0
  issueW(0, 0);
  writeX(px, 0);
  px = *(const float4*)(xp + 32);     // stage 1
  __syncthreads();                    // full drain ONCE: W(0)+x(0) landed

  for (int s = 0; s < 32; ++s) {
    const int p = s & 1;
    if (s < 31) {
      issueW(s + 1, p ^ 1);           // 6 gld16 -- fly across the barrier
      writeX(px, p ^ 1);              // px-use auto-waits vmcnt(6): W(s) landed
      if (s < 30) px = *(const float4*)(xp + (s + 2) * 32);
    } else {
      asm volatile("s_waitcnt vmcnt(0)" ::: "memory");  // tail: W(31) landed
    }
    __builtin_amdgcn_sched_barrier(0);  // ds_reads must stay below the waits

    bf16x8 ah0 = *(const bf16x8*)&XhSp(p)[swzi32(rA0, g)];
    bf16x8 ah1 = *(const bf16x8*)&XhSp(p)[swzi32(rA1, g)];
    bf16x8 al0 = *(const bf16x8*)&XlSp(p)[swzi32(rA0, g)];
    bf16x8 al1 = *(const bf16x8*)&XlSp(p)[swzi32(rA1, g)];
    bf16x8 bh0 = *(const bf16x8*)&WhSp(p)[swzi32(rB0, g)];
    bf16x8 bh1 = *(const bf16x8*)&WhSp(p)[swzi32(rB1, g)];
    bf16x8 bh2 = *(const bf16x8*)&WhSp(p)[swzi32(rB2, g)];
    bf16x8 bl0 = *(const bf16x8*)&WlSp(p)[swzi32(rB0, g)];
    bf16x8 bl1 = *(const bf16x8*)&WlSp(p)[swzi32(rB1, g)];
    bf16x8 bl2 = *(const bf16x8*)&WlSp(p)[swzi32(rB2, g)];

    __builtin_amdgcn_s_setprio(1);
    acc[0][0] = __builtin_amdgcn_mfma_f32_16x16x32_bf16(ah0, bh0, acc[0][0], 0,0,0);
    acc[0][0] = __builtin_amdgcn_mfma_f32_16x16x32_bf16(ah0, bl0, acc[0][0], 0,0,0);
    acc[0][0] = __builtin_amdgcn_mfma_f32_16x16x32_bf16(al0, bh0, acc[0][0], 0,0,0);
    acc[0][1] = __builtin_amdgcn_mfma_f32_16x16x32_bf16(ah0, bh1, acc[0][1], 0,0,0);
    acc[0][1] = __builtin_amdgcn_mfma_f32_16x16x32_bf16(ah0, bl1, acc[0][1], 0,0,0);
    acc[0][1] = __builtin_amdgcn_mfma_f32_16x16x32_bf16(al0, bh1, acc[0][1], 0,0,0);
    acc[0][2] = __builtin_amdgcn_mfma_f32_16x16x32_bf16(ah0, bh2, acc[0][2], 0,0,0);
    acc[0][2] = __builtin_amdgcn_mfma_f32_16x16x32_bf16(ah0, bl2, acc[0][2], 0,0,0);
    acc[0][2] = __builtin_amdgcn_mfma_f32_16x16x32_bf16(al0, bh2, acc[0][2], 0,0,0);
    acc[1][0] = __builtin_amdgcn_mfma_f32_16x16x32_bf16(ah1, bh0, acc[1][0], 0,0,0);
    acc[1][0] = __builtin_amdgcn_mfma_f32_16x16x32_bf16(ah1, bl0, acc[1][0], 0,0,0);
    acc[1][0] = __builtin_amdgcn_mfma_f32_16x16x32_bf16(al1, bh0, acc[1][0], 0,0,0);
    acc[1][1] = __builtin_amdgcn_mfma_f32_16x16x32_bf16(ah1, bh1, acc[1][1], 0,0,0);
    acc[1][1] = __builtin_amdgcn_mfma_f32_16x16x32_bf16(ah1, bl1, acc[1][1], 0,0,0);
    acc[1][1] = __builtin_amdgcn_mfma_f32_16x16x32_bf16(al1, bh1, acc[1][1], 0,0,0);
    acc[1][2] = __builtin_amdgcn_mfma_f32_16x16x32_bf16(ah1, bh2, acc[1][2], 0,0,0);
    acc[1][2] = __builtin_amdgcn_mfma_f32_16x16x32_bf16(ah1, bl2, acc[1][2], 0,0,0);
    acc[1][2] = __builtin_amdgcn_mfma_f32_16x16x32_bf16(al1, bh2, acc[1][2], 0,0,0);
    __builtin_amdgcn_s_setprio(0);

    // Raw barrier: X(s+1) ds_writes visible (lgkmcnt) WITHOUT draining the
    // in-flight W(s+1)/px vmem ops.
    asm volatile("s_waitcnt lgkmcnt(0)" ::: "memory");
    __builtin_amdgcn_s_barrier();
    __builtin_amdgcn_sched_barrier(0);
  }

  // Epilogue: D[m=16i+4g+r][n=48w+16j+li]
#pragma unroll
  for (int i = 0; i < 2; ++i)
#pragma unroll
    for (int j = 0; j < 3; ++j) {
      const int H3 = 48 * w + 16 * j + li;
#pragma unroll
      for (int r = 0; r < 4; ++r) {
        const int mrow = 16 * i + 4 * g + r;
        const float vv = acc[i][j][r];
        if (H3 < 64) {
          const unsigned short hb = f2bf(vv);
          const int off = (b * SEQ + n0 + mrow) * HS + H3;
          qh[off] = hb; ql[off] = f2bf(vv - bf2f(hb));
        } else if (H3 < 128) {
          const unsigned short hb = f2bf(vv);
          const int off = (b * SEQ + n0 + mrow) * HS + (H3 - 64);
          kh[off] = hb; kl[off] = f2bf(vv - bf2f(hb));
        } else {
          vt[(b * HS + (H3 - 128)) * SEQ + n0 + mrow] = f2bf(vv);
        }
      }
    }
}

// ---------------------------------------------------------------------------
// Flash attention, MFMA, cheap softmax (C-init=-32, truncated P, per-lane l).
// Grid (64, NB): 64 q-rows/block, 512 thr = 8 waves = 2 waves/SIMD.
// Wave w = (qg = w&1, ks = w>>1): 32 q x 32 keys of the 128-key tile; 32 it.
// K/V staging DOUBLE-BUFFERED (T3); ONE barrier/iter, drain after compute.
// NEW (round 5): P redistribution for PV is IN-REGISTER via __shfl
// (ds_bpermute, conflict-free) instead of the Pt LDS round-trip -- the Pt
// stride-40 int2 writes + b128 reads were the prime suspect for the 8.06M
// SQ_LDS_BANK_CONFLICT cycles (~23% of attn time). Mapping: dest lane
// (li,g) B-frag = keys 8g..8g+7 for kt=g>>1, held as packed bf16 pairs by
// source lanes li+32*(g&1) (j<4) and +16 (j>=4). 16 shfl + 8 selects/iter.
// Also frees 20KB LDS: 116 -> 96KB.
// ---------------------------------------------------------------------------
__global__ __launch_bounds__(512) void attn_mfma(
    const unsigned short* __restrict__ qh, const unsigned short* __restrict__ ql,
    const unsigned short* __restrict__ kh, const unsigned short* __restrict__ kl,
    const unsigned short* __restrict__ vt, float* __restrict__ out) {
  __shared__ __align__(16) unsigned char SM[98304];
  // layout: Kh[p] @ p*16384 (2x16KB), Kl[p] @ 32768+p*16384 (2x16KB),
  //         Vt[p] @ 65536+p*16384 (2x16KB)

  const int t  = threadIdx.x;
  const int l  = t & 63;
  const int li = l & 15;
  const int g  = l >> 4;
  const int w  = t >> 6;        // 0..7
  const int qg = w & 1;
  const int ks = w >> 1;        // key slice 0..3
  const int b  = blockIdx.y;
  const int q0 = blockIdx.x << 6;

  // Persistent Q fragments, 2 q-sets (B[k=h][n=q], n=li).
  bf16x8 qfh[2][2], qfl[2][2];
#pragma unroll
  for (int qs = 0; qs < 2; ++qs) {
    const unsigned short* qrh = qh + (b * SEQ + q0 + 32 * qg + 16 * qs + li) * HS;
    const unsigned short* qrl = ql + (b * SEQ + q0 + 32 * qg + 16 * qs + li) * HS;
    qfh[qs][0] = *(const bf16x8*)&qrh[8 * g];
    qfh[qs][1] = *(const bf16x8*)&qrh[32 + 8 * g];
    qfl[qs][0] = *(const bf16x8*)&qrl[8 * g];
    qfl[qs][1] = *(const bf16x8*)&qrl[32 + 8 * g];
  }

  // gld16 lane constants. K segs: 8 key-rows x 64 h = 1KB.
  const int kconst = (l >> 3) * HS + (((l & 7) ^ (l >> 3)) << 3);
  // V segs: 4 h-rows x 128 keys = 1KB; chunk perm depends on seg parity.
  const int rowl = l >> 4, slot = l & 15;
  const int vcE = rowl * SEQ + ((slot ^ rowl) << 3);
  const int vcO = rowl * SEQ + ((slot ^ (4 + rowl)) << 3);
  const unsigned short* khB = kh + b * SEQ * HS;
  const unsigned short* klB = kl + b * SEQ * HS;
  const unsigned short* vtB = vt + b * HS * SEQ;
  const int sA = 2 * w, sB = 2 * w + 1;   // this wave's 2 segs per array

  f32x4 O[4][2];
#pragma unroll
  for (int ht = 0; ht < 4; ++ht) {
    O[ht][0] = (f32x4){0.f, 0.f, 0.f, 0.f};
    O[ht][1] = (f32x4){0.f, 0.f, 0.f, 0.f};
  }
  float lp0 = 0.f, lp1 = 0.f;

  // P-exchange lane constants: sources for this dest lane's B-fragment
  const int sl0 = li + ((l & 16) << 1);   // li + 32*(g&1)  (j=0..3 source)
  const int sl1 = sl0 + 16;               //                (j=4..7 source)
  const bool kthi = (g >> 1) != 0;        // which kt this dest consumes

  // stage key-tile `it` into buffer p (issue only; NO wait here)
  auto stage = [&](int it, int p) {
    const int kt0 = it << 7;  // 128 keys per tile
    unsigned short* const KhP = (unsigned short*)(SM + p * 16384);
    unsigned short* const KlP = (unsigned short*)(SM + 32768 + p * 16384);
    unsigned short* const VtP = (unsigned short*)(SM + 65536 + p * 16384);
    gld16(khB + (kt0 + 8 * sA) * HS + kconst, KhP + sA * 512);
    gld16(khB + (kt0 + 8 * sB) * HS + kconst, KhP + sB * 512);
    gld16(klB + (kt0 + 8 * sA) * HS + kconst, KlP + sA * 512);
    gld16(klB + (kt0 + 8 * sB) * HS + kconst, KlP + sB * 512);
    gld16(vtB + 4 * sA * SEQ + kt0 + vcE, VtP + sA * 512);
    gld16(vtB + 4 * sB * SEQ + kt0 + vcO, VtP + sB * 512);
  };

  stage(0, 0);
  __syncthreads();            // drains tile 0 -> buf0 ready

  for (int it = 0; it < 32; ++it) {
    const int p = it & 1;
    if (it < 31) stage(it + 1, p ^ 1);   // flies during compute of tile it

    unsigned short* const KhS = (unsigned short*)(SM + p * 16384);
    unsigned short* const KlS = (unsigned short*)(SM + 32768 + p * 16384);
    unsigned short* const VtS = (unsigned short*)(SM + 65536 + p * 16384);

    // S[key][q]: wave's keys 32ks + 16kt + 4g + r; q-sets share A-reads.
    f32x4 S[2][2];
    S[0][0] = (f32x4){-32.f, -32.f, -32.f, -32.f};
    S[0][1] = (f32x4){-32.f, -32.f, -32.f, -32.f};
    S[1][0] = (f32x4){-32.f, -32.f, -32.f, -32.f};
    S[1][1] = (f32x4){-32.f, -32.f, -32.f, -32.f};
    __builtin_amdgcn_s_setprio(1);
#pragma unroll
    for (int khf = 0; khf < 2; ++khf) {
      const int cc = 4 * khf + g;
#pragma unroll
      for (int kt = 0; kt < 2; ++kt) {
        const int row = 32 * ks + 16 * kt + li;
        bf16x8 akh = *(const bf16x8*)&KhS[swzi64(row, cc)];
        bf16x8 akl = *(const bf16x8*)&KlS[swzi64(row, cc)];
        S[kt][0] = __builtin_amdgcn_mfma_f32_16x16x32_bf16(akh, qfh[0][khf], S[kt][0], 0,0,0);
        S[kt][0] = __builtin_amdgcn_mfma_f32_16x16x32_bf16(akh, qfl[0][khf], S[kt][0], 0,0,0);
        S[kt][0] = __builtin_amdgcn_mfma_f32_16x16x32_bf16(akl, qfh[0][khf], S[kt][0], 0,0,0);
        S[kt][1] = __builtin_amdgcn_mfma_f32_16x16x32_bf16(akh, qfh[1][khf], S[kt][1], 0,0,0);
        S[kt][1] = __builtin_amdgcn_mfma_f32_16x16x32_bf16(akh, qfl[1][khf], S[kt][1], 0,0,0);
        S[kt][1] = __builtin_amdgcn_mfma_f32_16x16x32_bf16(akl, qfh[1][khf], S[kt][1], 0,0,0);
      }
    }
    __builtin_amdgcn_s_setprio(0);

    // p = exp2(S'-32) truncated to bf16, packed [kt][qs] as 2 u32 each
    // (lo ushort = r=0/2 key, hi = r=1/3); l summed from truncated values.
    unsigned q01[2][2], q23[2][2];
#pragma unroll
    for (int kt = 0; kt < 2; ++kt)
#pragma unroll
      for (int qs = 0; qs < 2; ++qs) {
        unsigned pu[4];
        float ls = 0.f;
#pragma unroll
        for (int r = 0; r < 4; ++r) {
          const float pe = exp2f(S[kt][qs][r]);
          pu[r] = __float_as_uint(pe);
          ls += __uint_as_float(pu[r] & 0xffff0000u);
        }
        if (qs == 0) lp0 += ls; else lp1 += ls;
        q01[kt][qs] = __builtin_amdgcn_perm(pu[1], pu[0], 0x07060302u);
        q23[kt][qs] = __builtin_amdgcn_perm(pu[3], pu[2], 0x07060302u);
      }

    // In-register P redistribution (no LDS): dest (li,g) takes packed pairs
    // from lanes sl0 (keys 8g..8g+3) and sl1 (8g+4..8g+7), content kt=g>>1.
    bf16x8 pb0, pb1;
    {
      int A0 = __shfl((int)q01[0][0], sl0), B0 = __shfl((int)q01[1][0], sl0);
      int A1 = __shfl((int)q23[0][0], sl0), B1 = __shfl((int)q23[1][0], sl0);
      int A2 = __shfl((int)q01[0][0], sl1), B2 = __shfl((int)q01[1][0], sl1);
      int A3 = __shfl((int)q23[0][0], sl1), B3 = __shfl((int)q23[1][0], sl1);
      i32x4 t0 = { kthi ? B0 : A0, kthi ? B1 : A1,
                   kthi ? B2 : A2, kthi ? B3 : A3 };
      pb0 = __builtin_bit_cast(bf16x8, t0);
      int C0 = __shfl((int)q01[0][1], sl0), D0 = __shfl((int)q01[1][1], sl0);
      int C1 = __shfl((int)q23[0][1], sl0), D1 = __shfl((int)q23[1][1], sl0);
      int C2 = __shfl((int)q01[0][1], sl1), D2 = __shfl((int)q01[1][1], sl1);
      int C3 = __shfl((int)q23[0][1], sl1), D3 = __shfl((int)q23[1][1], sl1);
      i32x4 t1 = { kthi ? D0 : C0, kthi ? D1 : C1,
                   kthi ? D2 : C2, kthi ? D3 : C3 };
      pb1 = __builtin_bit_cast(bf16x8, t1);
    }

    // O^T += V^T . P over this wave's 32 keys.
    {
      __builtin_amdgcn_s_setprio(1);
#pragma unroll
      for (int ht = 0; ht < 4; ++ht) {
        const int vrow = 16 * ht + li;
        bf16x8 va = *(const bf16x8*)&VtS[swzi128(vrow, 4 * ks + g)];
        O[ht][0] = __builtin_amdgcn_mfma_f32_16x16x32_bf16(va, pb0, O[ht][0], 0,0,0);
        O[ht][1] = __builtin_amdgcn_mfma_f32_16x16x32_bf16(va, pb1, O[ht][1], 0,0,0);
      }
      __builtin_amdgcn_s_setprio(0);
    }

    // ONE barrier/iter: implicit vmcnt(0) drains tile it+1 (in flight
    // during all of compute) + guarantees buf[p] fully consumed before
    // re-staging. (Cross-wave consumption -> the drain IS required here.)
    __syncthreads();
  }

  // loop-final barrier: all waves done with staging -> reuse LDS for merge

  // reduce l over the 4 quads (keys) of this wave
  lp0 += __shfl_xor(lp0, 16); lp0 += __shfl_xor(lp0, 32);
  lp1 += __shfl_xor(lp1, 16); lp1 += __shfl_xor(lp1, 32);

  float* const OTm = (float*)SM;               // [8 waves][32 q][64 h] = 64KB
  float* const Lm  = (float*)(SM + 65536);     // [8 waves][32 q]
#pragma unroll
  for (int ht = 0; ht < 4; ++ht)
#pragma unroll
    for (int qs = 0; qs < 2; ++qs) {
      float4 o4;
      o4.x = O[ht][qs][0]; o4.y = O[ht][qs][1];
      o4.z = O[ht][qs][2]; o4.w = O[ht][qs][3];
      *(float4*)&OTm[w * 2048 + (16 * qs + li) * 64 + 16 * ht + 4 * g] = o4;
    }
  if (g == 0) { Lm[w * 32 + li] = lp0; Lm[w * 32 + 16 + li] = lp1; }
  __syncthreads();

  // final: thread t -> q = t>>3 (64), h8 = (t&7)*8; sum 4 key-slices.
  {
    const int q = t >> 3, h8 = (t & 7) << 3;
    const int qq = q & 31, qgf = q >> 5;
    float lF = 0.f;
    float4 a = {0.f, 0.f, 0.f, 0.f}, c4 = {0.f, 0.f, 0.f, 0.f};
#pragma unroll
    for (int k2 = 0; k2 < 4; ++k2) {
      const int ww = qgf + 2 * k2;
      lF += Lm[ww * 32 + qq];
      const float* Ob = OTm + ww * 2048 + qq * 64 + h8;
      float4 u = *(const float4*)Ob;
      float4 v = *(const float4*)(Ob + 4);
      a.x += u.x; a.y += u.y; a.z += u.z; a.w += u.w;
      c4.x += v.x; c4.y += v.y; c4.z += v.z; c4.w += v.w;
    }
    const float inv = 1.f / lF;
    a.x *= inv; a.y *= inv; a.z *= inv; a.w *= inv;
    c4.x *= inv; c4.y *= inv; c4.z *= inv; c4.w *= inv;
    float* op = out + (b * SEQ + q0 + q) * HS + h8;
    *(float4*)op = a;
    *(float4*)(op + 4) = c4;
  }
}

// ---------------------------------------------------------------------------
extern "C" void kernel_launch(void* const* d_in, const int* in_sizes, int n_in,
                              void* d_out, int out_size, void* d_ws,
                              size_t ws_size, hipStream_t stream) {
  const float* x  = (const float*)d_in[0];
  const float* Wk = (const float*)d_in[1];
  const float* Wq = (const float*)d_in[2];
  const float* Wv = (const float*)d_in[3];
  float* out = (float*)d_out;

  unsigned short* us = (unsigned short*)d_ws;
  unsigned short* qh = us + 0 * (1 << 20);   // [B][N][H] bf16 hi
  unsigned short* ql = us + 1 * (1 << 20);   // [B][N][H] bf16 lo
  unsigned short* kh = us + 2 * (1 << 20);
  unsigned short* kl = us + 3 * (1 << 20);
  unsigned short* vt = us + 4 * (1 << 20);   // [B][H][N] bf16
  unsigned short* Wh = us + 5 * (1 << 20);   // [192][1024] bf16 hi
  unsigned short* Wl = Wh + 192 * 1024;      // [192][1024] bf16 lo
  // total workspace: ~11 MB (proven available since round 3)

  wprep<<<192, 256, 0, stream>>>(Wk, Wq, Wv, Wh, Wl);
  qkv_x1<<<512, 256, 0, stream>>>(x, Wh, Wl, qh, ql, kh, kl, vt);
  attn_mfma<<<dim3(64, NB), 512, 0, stream>>>(qh, ql, kh, kl, vt, out);
}

// Round 6
// 183.811 us; speedup vs baseline: 1.1828x; 1.0128x over previous
//
#include <hip/hip_runtime.h>

#define NB   4
#define SEQ  4096
#define EMB  1024
#define HS   64

typedef __attribute__((ext_vector_type(8))) short bf16x8;   // 8 bf16 = 4 VGPRs
typedef __attribute__((ext_vector_type(4))) float f32x4;    // MFMA C/D

__device__ inline unsigned short f2bf(float f) {  // fp32 -> bf16 RNE
  unsigned int u = __float_as_uint(f);
  u += 0x7fffu + ((u >> 16) & 1u);
  return (unsigned short)(u >> 16);
}
__device__ inline float bf2f(unsigned short h) {
  return __uint_as_float(((unsigned int)h) << 16);
}
// 16B-chunk index in a [row][64] bf16 LDS tile, XOR-swizzled over row&7.
__device__ inline int swzi64(int row, int c) {
  return row * 64 + ((c ^ (row & 7)) << 3);
}
// same for [row][32] tiles (4 chunks/row, swizzle over (row>>1)&3)
__device__ inline int swzi32(int row, int c) {
  return row * 32 + ((c ^ ((row >> 1) & 3)) << 3);
}
// [row][128] tiles (16 chunks/row, swizzle over row&7)
__device__ inline int swzi128(int row, int c) {
  return row * 128 + ((c ^ (row & 7)) << 3);
}
// Async global->LDS 16B. LDS dest wave-uniform; lane i lands at +16*i.
__device__ inline void gld16(const unsigned short* g, unsigned short* l) {
  __builtin_amdgcn_global_load_lds(
      (const __attribute__((address_space(1))) void*)g,
      (__attribute__((address_space(3))) void*)l, 16, 0, 0);
}

// ---------------------------------------------------------------------------
// W prep: split Wq*scale*log2e | Wk | Wv into bf16 hi/lo [192][1024].
// ---------------------------------------------------------------------------
__global__ __launch_bounds__(256) void wprep(
    const float* __restrict__ Wk, const float* __restrict__ Wq,
    const float* __restrict__ Wv,
    unsigned short* __restrict__ Wh, unsigned short* __restrict__ Wl) {
  int i = blockIdx.x * 256 + threadIdx.x;  // float4 id, 192*1024/4 = 49152
  int e = i >> 8, c = i & 255;
  float4 v;
  float sc = 1.0f;
  if (e < 64)       { v = ((const float4*)Wq)[e * 256 + c];
                      sc = 0.18033688011112042f; }  // (1/sqrt(64))*log2(e)
  else if (e < 128)   v = ((const float4*)Wk)[(e - 64) * 256 + c];
  else                v = ((const float4*)Wv)[(e - 128) * 256 + c];
  v.x *= sc; v.y *= sc; v.z *= sc; v.w *= sc;
  ushort4 hv, lv;
  hv.x = f2bf(v.x); lv.x = f2bf(v.x - bf2f(hv.x));
  hv.y = f2bf(v.y); lv.y = f2bf(v.y - bf2f(hv.y));
  hv.z = f2bf(v.z); lv.z = f2bf(v.z - bf2f(hv.z));
  hv.w = f2bf(v.w); lv.w = f2bf(v.w - bf2f(hv.w));
  *(ushort4*)&Wh[i * 4] = hv;
  *(ushort4*)&Wl[i * 4] = lv;
}

// ---------------------------------------------------------------------------
// Single-pass fused QKV GEMM (round-2 structure, best measured 58.4 us):
// C[32 x 192] per block = x-tile . [Wq|Wk|Wv]^T, split-bf16
// (acc += Ah.Bh + Ah.Bl + Al.Bh). Grid 512, 256 thr = 4 waves,
// wave w owns n-range [48w, 48w+48) x full m=32 (2x3 16x16 C-tiles).
// BK=32, 32 stages, double-buffered; counted-vmcnt pipeline (T4): wave w
// consumes ONLY the W segments it stages itself, so W sync is per-wave
// vmcnt; loop barrier is raw lgkmcnt(0)+s_barrier (X ds_write visibility),
// NO vmcnt(0) drain. writeX(px) use auto-inserts vmcnt(6).
// ---------------------------------------------------------------------------
#define XhSp(p) ((unsigned short*)(SM + (p) * 2048))
#define XlSp(p) ((unsigned short*)(SM + 4096 + (p) * 2048))
#define WhSp(p) ((unsigned short*)(SM + 8192 + (p) * 12288))
#define WlSp(p) ((unsigned short*)(SM + 32768 + (p) * 12288))

__global__ __launch_bounds__(256) void qkv_x1(
    const float* __restrict__ x,
    const unsigned short* __restrict__ Wh, const unsigned short* __restrict__ Wl,
    unsigned short* __restrict__ qh, unsigned short* __restrict__ ql,
    unsigned short* __restrict__ kh, unsigned short* __restrict__ kl,
    unsigned short* __restrict__ vt) {
  __shared__ __align__(16) unsigned char SM[57344];

  const int t  = threadIdx.x;
  const int l  = t & 63;
  const int li = l & 15;
  const int g  = l >> 4;
  const int w  = t >> 6;         // 0..3
  const int m0 = blockIdx.x * 32;
  const int b  = m0 >> 12;
  const int n0 = m0 & 4095;

  // x load/convert map: thread -> one float4 of the 32x32 tile
  const int xrow = t >> 3;
  const float* xp = x + (m0 + xrow) * EMB + (t & 7) * 4;
  const int xaddr = xrow * 32 + ((((t & 7) >> 1) ^ ((xrow >> 1) & 3)) << 3)
                    + (t & 1) * 4;

  // W gld16 lane-constant (seg = 16 W-rows x 32 k = 1KB)
  const int wconst = (l >> 2) * EMB + (((l & 3) ^ ((l >> 3) & 3)) << 3);

  f32x4 acc[2][3];
#pragma unroll
  for (int i = 0; i < 2; ++i)
#pragma unroll
    for (int j = 0; j < 3; ++j) acc[i][j] = (f32x4){0.f, 0.f, 0.f, 0.f};

  const int rA0 = li, rA1 = 16 + li;
  const int rB0 = 48 * w + li, rB1 = rB0 + 16, rB2 = rB0 + 32;

  auto issueW = [&](int s, int p) {
    const int ko = s * 32;
#pragma unroll
    for (int i = 0; i < 3; ++i) {
      const int seg = 3 * w + i;
      gld16(Wh + 16 * seg * EMB + wconst + ko, WhSp(p) + seg * 512);
      gld16(Wl + 16 * seg * EMB + wconst + ko, WlSp(p) + seg * 512);
    }
  };
  auto writeX = [&](float4 v, int p) {
    unsigned short h0 = f2bf(v.x), h1 = f2bf(v.y), h2 = f2bf(v.z), h3 = f2bf(v.w);
    unsigned short e0 = f2bf(v.x - bf2f(h0)), e1 = f2bf(v.y - bf2f(h1));
    unsigned short e2 = f2bf(v.z - bf2f(h2)), e3 = f2bf(v.w - bf2f(h3));
    int2 hv, lv;
    hv.x = (int)((unsigned)h0 | ((unsigned)h1 << 16));
    hv.y = (int)((unsigned)h2 | ((unsigned)h3 << 16));
    lv.x = (int)((unsigned)e0 | ((unsigned)e1 << 16));
    lv.y = (int)((unsigned)e2 | ((unsigned)e3 << 16));
    *(int2*)&XhSp(p)[xaddr] = hv;
    *(int2*)&XlSp(p)[xaddr] = lv;
  };

  float4 px = *(const float4*)xp;     // stage 0
  issueW(0, 0);
  writeX(px, 0);
  px = *(const float4*)(xp + 32);     // stage 1
  __syncthreads();                    // full drain ONCE: W(0)+x(0) landed

  for (int s = 0; s < 32; ++s) {
    const int p = s & 1;
    if (s < 31) {
      issueW(s + 1, p ^ 1);           // 6 gld16 -- fly across the barrier
      writeX(px, p ^ 1);              // px-use auto-waits vmcnt(6): W(s) landed
      if (s < 30) px = *(const float4*)(xp + (s + 2) * 32);
    } else {
      asm volatile("s_waitcnt vmcnt(0)" ::: "memory");  // tail: W(31) landed
    }
    __builtin_amdgcn_sched_barrier(0);  // ds_reads must stay below the waits

    bf16x8 ah0 = *(const bf16x8*)&XhSp(p)[swzi32(rA0, g)];
    bf16x8 ah1 = *(const bf16x8*)&XhSp(p)[swzi32(rA1, g)];
    bf16x8 al0 = *(const bf16x8*)&XlSp(p)[swzi32(rA0, g)];
    bf16x8 al1 = *(const bf16x8*)&XlSp(p)[swzi32(rA1, g)];
    bf16x8 bh0 = *(const bf16x8*)&WhSp(p)[swzi32(rB0, g)];
    bf16x8 bh1 = *(const bf16x8*)&WhSp(p)[swzi32(rB1, g)];
    bf16x8 bh2 = *(const bf16x8*)&WhSp(p)[swzi32(rB2, g)];
    bf16x8 bl0 = *(const bf16x8*)&WlSp(p)[swzi32(rB0, g)];
    bf16x8 bl1 = *(const bf16x8*)&WlSp(p)[swzi32(rB1, g)];
    bf16x8 bl2 = *(const bf16x8*)&WlSp(p)[swzi32(rB2, g)];

    __builtin_amdgcn_s_setprio(1);
    acc[0][0] = __builtin_amdgcn_mfma_f32_16x16x32_bf16(ah0, bh0, acc[0][0], 0,0,0);
    acc[0][0] = __builtin_amdgcn_mfma_f32_16x16x32_bf16(ah0, bl0, acc[0][0], 0,0,0);
    acc[0][0] = __builtin_amdgcn_mfma_f32_16x16x32_bf16(al0, bh0, acc[0][0], 0,0,0);
    acc[0][1] = __builtin_amdgcn_mfma_f32_16x16x32_bf16(ah0, bh1, acc[0][1], 0,0,0);
    acc[0][1] = __builtin_amdgcn_mfma_f32_16x16x32_bf16(ah0, bl1, acc[0][1], 0,0,0);
    acc[0][1] = __builtin_amdgcn_mfma_f32_16x16x32_bf16(al0, bh1, acc[0][1], 0,0,0);
    acc[0][2] = __builtin_amdgcn_mfma_f32_16x16x32_bf16(ah0, bh2, acc[0][2], 0,0,0);
    acc[0][2] = __builtin_amdgcn_mfma_f32_16x16x32_bf16(ah0, bl2, acc[0][2], 0,0,0);
    acc[0][2] = __builtin_amdgcn_mfma_f32_16x16x32_bf16(al0, bh2, acc[0][2], 0,0,0);
    acc[1][0] = __builtin_amdgcn_mfma_f32_16x16x32_bf16(ah1, bh0, acc[1][0], 0,0,0);
    acc[1][0] = __builtin_amdgcn_mfma_f32_16x16x32_bf16(ah1, bl0, acc[1][0], 0,0,0);
    acc[1][0] = __builtin_amdgcn_mfma_f32_16x16x32_bf16(al1, bh0, acc[1][0], 0,0,0);
    acc[1][1] = __builtin_amdgcn_mfma_f32_16x16x32_bf16(ah1, bh1, acc[1][1], 0,0,0);
    acc[1][1] = __builtin_amdgcn_mfma_f32_16x16x32_bf16(ah1, bl1, acc[1][1], 0,0,0);
    acc[1][1] = __builtin_amdgcn_mfma_f32_16x16x32_bf16(al1, bh1, acc[1][1], 0,0,0);
    acc[1][2] = __builtin_amdgcn_mfma_f32_16x16x32_bf16(ah1, bh2, acc[1][2], 0,0,0);
    acc[1][2] = __builtin_amdgcn_mfma_f32_16x16x32_bf16(ah1, bl2, acc[1][2], 0,0,0);
    acc[1][2] = __builtin_amdgcn_mfma_f32_16x16x32_bf16(al1, bh2, acc[1][2], 0,0,0);
    __builtin_amdgcn_s_setprio(0);

    // Raw barrier: X(s+1) ds_writes visible (lgkmcnt) WITHOUT draining the
    // in-flight W(s+1)/px vmem ops.
    asm volatile("s_waitcnt lgkmcnt(0)" ::: "memory");
    __builtin_amdgcn_s_barrier();
    __builtin_amdgcn_sched_barrier(0);
  }

  // Epilogue: D[m=16i+4g+r][n=48w+16j+li]
#pragma unroll
  for (int i = 0; i < 2; ++i)
#pragma unroll
    for (int j = 0; j < 3; ++j) {
      const int H3 = 48 * w + 16 * j + li;
#pragma unroll
      for (int r = 0; r < 4; ++r) {
        const int mrow = 16 * i + 4 * g + r;
        const float vv = acc[i][j][r];
        if (H3 < 64) {
          const unsigned short hb = f2bf(vv);
          const int off = (b * SEQ + n0 + mrow) * HS + H3;
          qh[off] = hb; ql[off] = f2bf(vv - bf2f(hb));
        } else if (H3 < 128) {
          const unsigned short hb = f2bf(vv);
          const int off = (b * SEQ + n0 + mrow) * HS + (H3 - 64);
          kh[off] = hb; kl[off] = f2bf(vv - bf2f(hb));
        } else {
          vt[(b * HS + (H3 - 128)) * SEQ + n0 + mrow] = f2bf(vv);
        }
      }
    }
}

// ---------------------------------------------------------------------------
// Flash attention, MFMA, cheap softmax (C-init=-32, truncated P, per-lane l).
// Grid (64, NB): 64 q-rows/block, 512 thr = 8 waves = 2 waves/SIMD.
// Wave w = (qg = w&1, ks = w>>1): 32 q x 32 keys of the 128-key tile; 32 it.
// K/V staging double-buffered (K 2-deep, V 3-deep); ONE barrier/iter.
// NEW (round 6, T15 att[2] double-pipeline): PV is DEFERRED one iteration.
// Iter t: stage(t+1) -> QK^T(t) -> PV(t-1) -> exp(t)+PtW(t) -> barrier.
// PV(t-1) (8 MFMA + Pt/V LDS reads) is independent of S(t), so the
// scheduler overlaps it with the serial 16x v_exp chain (separate pipes).
// V 3-buffer: iter t writes V[(t+1)%3], reads V[(t-1)%3] (distance 2, safe).
// Pt 2-slab/wave: write slab t&1, read slab (t-1)&1. Epilogue runs PV(31).
// LDS 152KB -> 1 block/CU (unchanged occupancy).
// ---------------------------------------------------------------------------
__global__ __launch_bounds__(512) void attn_mfma(
    const unsigned short* __restrict__ qh, const unsigned short* __restrict__ ql,
    const unsigned short* __restrict__ kh, const unsigned short* __restrict__ kl,
    const unsigned short* __restrict__ vt, float* __restrict__ out) {
  __shared__ __align__(16) unsigned char SM[155648];
  // layout: Kh[p] @ p*16384 (2x16KB)           [0 .. 32K)
  //         Kl[p] @ 32768 + p*16384 (2x16KB)   [32K .. 64K)
  //         Vt[v] @ 65536 + v*16384 (3x16KB)   [64K .. 112K)
  //         Pt    @ 114688, 8 waves x 2 slabs x 1280 ush (40KB)
  unsigned short* const PtS = (unsigned short*)(SM + 114688);

  const int t  = threadIdx.x;
  const int l  = t & 63;
  const int li = l & 15;
  const int g  = l >> 4;
  const int w  = t >> 6;        // 0..7
  const int qg = w & 1;
  const int ks = w >> 1;        // key slice 0..3
  const int b  = blockIdx.y;
  const int q0 = blockIdx.x << 6;

  // Persistent Q fragments, 2 q-sets (B[k=h][n=q], n=li).
  bf16x8 qfh[2][2], qfl[2][2];
#pragma unroll
  for (int qs = 0; qs < 2; ++qs) {
    const unsigned short* qrh = qh + (b * SEQ + q0 + 32 * qg + 16 * qs + li) * HS;
    const unsigned short* qrl = ql + (b * SEQ + q0 + 32 * qg + 16 * qs + li) * HS;
    qfh[qs][0] = *(const bf16x8*)&qrh[8 * g];
    qfh[qs][1] = *(const bf16x8*)&qrh[32 + 8 * g];
    qfl[qs][0] = *(const bf16x8*)&qrl[8 * g];
    qfl[qs][1] = *(const bf16x8*)&qrl[32 + 8 * g];
  }

  // gld16 lane constants. K segs: 8 key-rows x 64 h = 1KB.
  const int kconst = (l >> 3) * HS + (((l & 7) ^ (l >> 3)) << 3);
  // V segs: 4 h-rows x 128 keys = 1KB; chunk perm depends on seg parity.
  const int rowl = l >> 4, slot = l & 15;
  const int vcE = rowl * SEQ + ((slot ^ rowl) << 3);
  const int vcO = rowl * SEQ + ((slot ^ (4 + rowl)) << 3);
  const unsigned short* khB = kh + b * SEQ * HS;
  const unsigned short* klB = kl + b * SEQ * HS;
  const unsigned short* vtB = vt + b * HS * SEQ;
  const int sA = 2 * w, sB = 2 * w + 1;   // this wave's 2 segs per array

  f32x4 O[4][2];
#pragma unroll
  for (int ht = 0; ht < 4; ++ht) {
    O[ht][0] = (f32x4){0.f, 0.f, 0.f, 0.f};
    O[ht][1] = (f32x4){0.f, 0.f, 0.f, 0.f};
  }
  float lp0 = 0.f, lp1 = 0.f;

  // stage key-tile `it`: K into K[pK], V into V[vb] (issue only, NO wait)
  auto stage = [&](int it, int pK, int vb) {
    const int kt0 = it << 7;  // 128 keys per tile
    unsigned short* const KhP = (unsigned short*)(SM + pK * 16384);
    unsigned short* const KlP = (unsigned short*)(SM + 32768 + pK * 16384);
    unsigned short* const VtP = (unsigned short*)(SM + 65536 + vb * 16384);
    gld16(khB + (kt0 + 8 * sA) * HS + kconst, KhP + sA * 512);
    gld16(khB + (kt0 + 8 * sB) * HS + kconst, KhP + sB * 512);
    gld16(klB + (kt0 + 8 * sA) * HS + kconst, KlP + sA * 512);
    gld16(klB + (kt0 + 8 * sB) * HS + kconst, KlP + sB * 512);
    gld16(vtB + 4 * sA * SEQ + kt0 + vcE, VtP + sA * 512);
    gld16(vtB + 4 * sB * SEQ + kt0 + vcO, VtP + sB * 512);
  };

  // PV of a prior tile: Pt slab `slab`, V buffer `vb`.
  auto PV = [&](int slab, int vb) {
    unsigned short* const PtP = PtS + w * 2560 + slab * 1280;
    unsigned short* const VtP = (unsigned short*)(SM + 65536 + vb * 16384);
    bf16x8 pb0 = *(const bf16x8*)&PtP[li * 40 + ((g ^ (li & 3)) << 3)];
    const int r1 = 16 + li;
    bf16x8 pb1 = *(const bf16x8*)&PtP[r1 * 40 + ((g ^ (r1 & 3)) << 3)];
    __builtin_amdgcn_s_setprio(1);
#pragma unroll
    for (int ht = 0; ht < 4; ++ht) {
      const int vrow = 16 * ht + li;
      bf16x8 va = *(const bf16x8*)&VtP[swzi128(vrow, 4 * ks + g)];
      O[ht][0] = __builtin_amdgcn_mfma_f32_16x16x32_bf16(va, pb0, O[ht][0], 0,0,0);
      O[ht][1] = __builtin_amdgcn_mfma_f32_16x16x32_bf16(va, pb1, O[ht][1], 0,0,0);
    }
    __builtin_amdgcn_s_setprio(0);
  };

  stage(0, 0, 0);
  __syncthreads();            // drains tile 0 -> K[0], V[0] ready

  int vbn = 1;                // (it+1)%3
  int vbp = 2;                // (it-1)%3 (value at it=0 unused)
  for (int it = 0; it < 32; ++it) {
    const int p = it & 1;
    if (it < 31) stage(it + 1, p ^ 1, vbn);  // flies during compute of tile it

    unsigned short* const KhS = (unsigned short*)(SM + p * 16384);
    unsigned short* const KlS = (unsigned short*)(SM + 32768 + p * 16384);

    // S[key][q]: wave's keys 32ks + 16kt + 4g + r; q-sets share A-reads.
    f32x4 S[2][2];
    S[0][0] = (f32x4){-32.f, -32.f, -32.f, -32.f};
    S[0][1] = (f32x4){-32.f, -32.f, -32.f, -32.f};
    S[1][0] = (f32x4){-32.f, -32.f, -32.f, -32.f};
    S[1][1] = (f32x4){-32.f, -32.f, -32.f, -32.f};
    __builtin_amdgcn_s_setprio(1);
#pragma unroll
    for (int khf = 0; khf < 2; ++khf) {
      const int cc = 4 * khf + g;
#pragma unroll
      for (int kt = 0; kt < 2; ++kt) {
        const int row = 32 * ks + 16 * kt + li;
        bf16x8 akh = *(const bf16x8*)&KhS[swzi64(row, cc)];
        bf16x8 akl = *(const bf16x8*)&KlS[swzi64(row, cc)];
        S[kt][0] = __builtin_amdgcn_mfma_f32_16x16x32_bf16(akh, qfh[0][khf], S[kt][0], 0,0,0);
        S[kt][0] = __builtin_amdgcn_mfma_f32_16x16x32_bf16(akh, qfl[0][khf], S[kt][0], 0,0,0);
        S[kt][0] = __builtin_amdgcn_mfma_f32_16x16x32_bf16(akl, qfh[0][khf], S[kt][0], 0,0,0);
        S[kt][1] = __builtin_amdgcn_mfma_f32_16x16x32_bf16(akh, qfh[1][khf], S[kt][1], 0,0,0);
        S[kt][1] = __builtin_amdgcn_mfma_f32_16x16x32_bf16(akh, qfl[1][khf], S[kt][1], 0,0,0);
        S[kt][1] = __builtin_amdgcn_mfma_f32_16x16x32_bf16(akl, qfh[1][khf], S[kt][1], 0,0,0);
      }
    }
    __builtin_amdgcn_s_setprio(0);

    // PV of PREVIOUS tile: independent of S(t) -> overlaps the exp chain.
    if (it > 0) PV(p ^ 1, vbp);

    // p = exp2(S'-32), truncate to bf16, write Pt slab p; l from truncated.
    unsigned short* const PtW = PtS + w * 2560 + p * 1280;
#pragma unroll
    for (int kt = 0; kt < 2; ++kt)
#pragma unroll
      for (int qs = 0; qs < 2; ++qs) {
        unsigned pu[4];
        float ls = 0.f;
#pragma unroll
        for (int r = 0; r < 4; ++r) {
          const float pe = exp2f(S[kt][qs][r]);
          pu[r] = __float_as_uint(pe);
          ls += __uint_as_float(pu[r] & 0xffff0000u);
        }
        if (qs == 0) lp0 += ls; else lp1 += ls;
        const unsigned p01 = __builtin_amdgcn_perm(pu[1], pu[0], 0x07060302u);
        const unsigned p23 = __builtin_amdgcn_perm(pu[3], pu[2], 0x07060302u);
        const int qrow = 16 * qs + li;
        const int c = 2 * kt + (g >> 1);
        const int addr = qrow * 40 + (((c ^ (qrow & 3))) << 3) + ((g & 1) << 2);
        int2 pv; pv.x = (int)p01; pv.y = (int)p23;
        *(int2*)&PtW[addr] = pv;
      }

    // ONE barrier/iter: implicit vmcnt(0) drains tile it+1 (in flight during
    // compute) + orders Pt slab writes for next iter's PV + protects K/V
    // buffer reuse. (Cross-wave consumption -> the drain IS required.)
    __syncthreads();

    vbn = (vbn == 2) ? 0 : vbn + 1;
    vbp = (vbp == 2) ? 0 : vbp + 1;
  }

  // Drain the pipeline: PV of tile 31 (Pt slab 31&1=1, V[31%3=1]).
  PV(1, 1);

  // reduce l over the 4 quads (keys) of this wave
  lp0 += __shfl_xor(lp0, 16); lp0 += __shfl_xor(lp0, 32);
  lp1 += __shfl_xor(lp1, 16); lp1 += __shfl_xor(lp1, 32);

  // Merge via LDS reuse: OTm in [0,64K) (K buffers, all consumed), Lm just
  // above -- neither overlaps V[1]/Pt which PV(31) reads (>= 80K).
  float* const OTm = (float*)SM;               // [8 waves][32 q][64 h] = 64KB
  float* const Lm  = (float*)(SM + 65536);     // [8 waves][32 q]
#pragma unroll
  for (int ht = 0; ht < 4; ++ht)
#pragma unroll
    for (int qs = 0; qs < 2; ++qs) {
      float4 o4;
      o4.x = O[ht][qs][0]; o4.y = O[ht][qs][1];
      o4.z = O[ht][qs][2]; o4.w = O[ht][qs][3];
      *(float4*)&OTm[w * 2048 + (16 * qs + li) * 64 + 16 * ht + 4 * g] = o4;
    }
  if (g == 0) { Lm[w * 32 + li] = lp0; Lm[w * 32 + 16 + li] = lp1; }
  __syncthreads();

  // final: thread t -> q = t>>3 (64), h8 = (t&7)*8; sum 4 key-slices.
  {
    const int q = t >> 3, h8 = (t & 7) << 3;
    const int qq = q & 31, qgf = q >> 5;
    float lF = 0.f;
    float4 a = {0.f, 0.f, 0.f, 0.f}, c4 = {0.f, 0.f, 0.f, 0.f};
#pragma unroll
    for (int k2 = 0; k2 < 4; ++k2) {
      const int ww = qgf + 2 * k2;
      lF += Lm[ww * 32 + qq];
      const float* Ob = OTm + ww * 2048 + qq * 64 + h8;
      float4 u = *(const float4*)Ob;
      float4 v = *(const float4*)(Ob + 4);
      a.x += u.x; a.y += u.y; a.z += u.z; a.w += u.w;
      c4.x += v.x; c4.y += v.y; c4.z += v.z; c4.w += v.w;
    }
    const float inv = 1.f / lF;
    a.x *= inv; a.y *= inv; a.z *= inv; a.w *= inv;
    c4.x *= inv; c4.y *= inv; c4.z *= inv; c4.w *= inv;
    float* op = out + (b * SEQ + q0 + q) * HS + h8;
    *(float4*)op = a;
    *(float4*)(op + 4) = c4;
  }
}

// ---------------------------------------------------------------------------
extern "C" void kernel_launch(void* const* d_in, const int* in_sizes, int n_in,
                              void* d_out, int out_size, void* d_ws,
                              size_t ws_size, hipStream_t stream) {
  const float* x  = (const float*)d_in[0];
  const float* Wk = (const float*)d_in[1];
  const float* Wq = (const float*)d_in[2];
  const float* Wv = (const float*)d_in[3];
  float* out = (float*)d_out;

  unsigned short* us = (unsigned short*)d_ws;
  unsigned short* qh = us + 0 * (1 << 20);   // [B][N][H] bf16 hi
  unsigned short* ql = us + 1 * (1 << 20);   // [B][N][H] bf16 lo
  unsigned short* kh = us + 2 * (1 << 20);
  unsigned short* kl = us + 3 * (1 << 20);
  unsigned short* vt = us + 4 * (1 << 20);   // [B][H][N] bf16
  unsigned short* Wh = us + 5 * (1 << 20);   // [192][1024] bf16 hi
  unsigned short* Wl = Wh + 192 * 1024;      // [192][1024] bf16 lo
  // total workspace: ~11 MB (proven available since round 3)

  wprep<<<192, 256, 0, stream>>>(Wk, Wq, Wv, Wh, Wl);
  qkv_x1<<<512, 256, 0, stream>>>(x, Wh, Wl, qh, ql, kh, kl, vt);
  attn_mfma<<<dim3(64, NB), 512, 0, stream>>>(qh, ql, kh, kl, vt, out);
}